// Round 11
// baseline (135.754 us; speedup 1.0000x reference)
//
#include <hip/hip_runtime.h>
#include <cmath>

#define BATCH 8
#define SEQ   2048
#define NEMB  2048
#define HD    128
#define NROWS (BATCH * SEQ)   // 16384

typedef __bf16 v8bf __attribute__((ext_vector_type(8)));
typedef float  f32x4 __attribute__((ext_vector_type(4)));

union U8 { v8bf v; __bf16 b[8]; unsigned short e[8]; };
union F4 { f32x4 v; float f[4]; };

__device__ inline void async16(void* lds, const void* g) {
  __builtin_amdgcn_global_load_lds(
      (const __attribute__((address_space(1))) unsigned int*)g,
      (__attribute__((address_space(3))) unsigned int*)lds, 16, 0, 0);
}

__device__ inline v8bf cvt8(float4 a, float4 b) {
  U8 u;
  u.b[0] = (__bf16)a.x; u.b[1] = (__bf16)a.y; u.b[2] = (__bf16)a.z; u.b[3] = (__bf16)a.w;
  u.b[4] = (__bf16)b.x; u.b[5] = (__bf16)b.y; u.b[6] = (__bf16)b.z; u.b[7] = (__bf16)b.w;
  return u.v;
}

// ---------------- W fp32 -> bf16 (3 x 128 x 2048) ----------------
__global__ __launch_bounds__(256) void wconv_kernel(
    const float* __restrict__ Wq, const float* __restrict__ Wk,
    const float* __restrict__ Wv, __bf16* __restrict__ out) {
  const int id = blockIdx.x;                 // 3 * 64 blocks
  const int proj = id >> 6, blk = id & 63;
  const float* __restrict__ W = proj == 0 ? Wq : proj == 1 ? Wk : Wv;
  __bf16* __restrict__ o = out + (size_t)proj * (HD * NEMB);
  const int base = blk * 4096 + threadIdx.x * 16;
  const float4* s = (const float4*)(W + base);
  float4 f0 = s[0], f1 = s[1], f2 = s[2], f3 = s[3];
  *(v8bf*)(o + base) = cvt8(f0, f1);
  *(v8bf*)(o + base + 8) = cvt8(f2, f3);
}

// ---------------- QKV projection: r7 structure + in-block split-K --------
// 512 thr / 8 waves: waves 0-3 -> K[0,1024), waves 4-7 -> K[1024,2048),
// same 64x128 output tile. Per half: A fp32 [64][64] + B bf16 [128][64],
// r7 DMA staging (inverse-swizzled src, linear LDS dest), 2 barriers/step,
// 16 steps. Epilogue: half-1 accs via LDS, half-0 adds + bias + store.
// LDS 64 KB -> 2 blocks/CU = 16 waves/CU (4/SIMD).
__global__ __launch_bounds__(512, 4) void qkv_proj_kernel(
    const float* __restrict__ x, const __bf16* __restrict__ Wb,
    const float* __restrict__ bq, const float* __restrict__ bk,
    const float* __restrict__ bv,
    __bf16* __restrict__ Qb, __bf16* __restrict__ Kb, __bf16* __restrict__ Vb)
{
  const int bid0 = blockIdx.x;
  const int bid = ((bid0 & 7) * 96) + (bid0 >> 3);   // 768 % 8 == 0
  const int mt = bid / 3;
  const int proj = bid % 3;
  const __bf16* __restrict__ W = Wb + (size_t)proj * (HD * NEMB);
  const float* __restrict__ bias = proj == 0 ? bq : proj == 1 ? bk : bv;
  __bf16* __restrict__ Out = proj == 0 ? Qb : proj == 1 ? Kb : Vb;
  const int m0 = mt * 64;

  __shared__ char smem[65536];
  // layout: A half0 [0,16K) | A half1 [16K,32K) | B half0 [32K,48K) | B half1 [48K,64K)
  // epilogue reuse: red = smem[0,32K)

  const int t = threadIdx.x, lane = t & 63, w = t >> 6;
  const int kh = w >> 2, wsub = w & 3;
  const int wm = wsub >> 1, wn = wsub & 1;
  const int hi = lane >> 4, lo = lane & 15;
  const int kbase = kh * 1024;

  char* Abase = smem + kh * 16384;
  char* Bbase = smem + 32768 + kh * 16384;

  // staging pointers: 4 A-chunks + 4 B-chunks per wave, 1 KB each
  const float* pa[4];
  const __bf16* pb[4];
  char* la[4];
  char* lb[4];
#pragma unroll
  for (int i = 0; i < 4; ++i) {
    {  // A chunk (wsub*4+i): 4 rows x 256B
      const int j = wsub * 4 + i;
      const int r = j * 4 + (lane >> 4);
      const int c = (lane & 15) ^ (r & 7);
      pa[i] = x + (size_t)(m0 + r) * NEMB + kbase + c * 4;
      la[i] = Abase + j * 1024;
    }
    {  // B chunk: 8 rows x 128B
      const int j = wsub * 4 + i;
      const int r = j * 8 + (lane >> 3);
      const int c = (lane & 7) ^ (r & 7);
      pb[i] = W + (size_t)r * NEMB + kbase + c * 8;
      lb[i] = Bbase + j * 1024;
    }
  }

  f32x4 acc[2][4];
  const f32x4 fz = {0.f, 0.f, 0.f, 0.f};
#pragma unroll
  for (int m = 0; m < 2; ++m)
#pragma unroll
    for (int n = 0; n < 4; ++n) acc[m][n] = fz;

  for (int tt = 0; tt < 16; ++tt) {        // 16 steps of BK=64 per half
    const int k0 = tt * 64;
    __syncthreads();   // previous compute done -> safe to overwrite tiles
#pragma unroll
    for (int i = 0; i < 4; ++i) async16(la[i], pa[i] + k0);
#pragma unroll
    for (int i = 0; i < 4; ++i) async16(lb[i], pb[i] + k0);
    __syncthreads();   // drain: tile tt resident

#pragma unroll
    for (int kk = 0; kk < 2; ++kk) {
      v8bf a[2], b[4];
#pragma unroll
      for (int m = 0; m < 2; ++m) {
        const int r = wm * 32 + m * 16 + lo;
        const int s = kk * 8 + hi * 2;
        const char* rowp = (const char*)Abase + r * 256;
        F4 a0, a1;
        a0.v = *(const f32x4*)(rowp + (((s)     ^ (r & 7)) << 4));
        a1.v = *(const f32x4*)(rowp + (((s + 1) ^ (r & 7)) << 4));
        U8 u;
#pragma unroll
        for (int q = 0; q < 4; ++q) {
          u.b[q]     = (__bf16)a0.f[q];
          u.b[q + 4] = (__bf16)a1.f[q];
        }
        a[m] = u.v;
      }
#pragma unroll
      for (int n = 0; n < 4; ++n) {
        const int r = wn * 64 + n * 16 + lo;
        const int kc = kk * 4 + hi;
        b[n] = *(const v8bf*)((const char*)Bbase + r * 128 + ((kc ^ (r & 7)) << 4));
      }
#pragma unroll
      for (int m = 0; m < 2; ++m)
#pragma unroll
        for (int n = 0; n < 4; ++n)
          acc[m][n] = __builtin_amdgcn_mfma_f32_16x16x32_bf16(a[m], b[n], acc[m][n], 0, 0, 0);
    }
  }

  // ---- cross-half reduction: half-1 -> LDS, half-0 adds + bias + store ----
  __syncthreads();   // all compute done; smem[0,32K) is dead -> reuse
  float* red = (float*)smem;
  if (kh == 1) {
    float* dst = red + (wsub * 64 + lane) * 32;
#pragma unroll
    for (int m = 0; m < 2; ++m)
#pragma unroll
      for (int n = 0; n < 4; ++n)
#pragma unroll
        for (int r = 0; r < 4; ++r)
          dst[(m * 4 + n) * 4 + r] = acc[m][n][r];
  }
  __syncthreads();
  if (kh == 0) {
    const float* src = red + (wsub * 64 + lane) * 32;
#pragma unroll
    for (int n = 0; n < 4; ++n) {
      const int col = wn * 64 + n * 16 + lo;
      const float bi = bias[col];
#pragma unroll
      for (int m = 0; m < 2; ++m) {
#pragma unroll
        for (int r = 0; r < 4; ++r) {
          const int row = m0 + wm * 32 + m * 16 + hi * 4 + r;
          Out[(size_t)row * HD + col] =
              (__bf16)(acc[m][n][r] + src[(m * 4 + n) * 4 + r] + bi);
        }
      }
    }
  }
}

// ---------------- Flash attention, split-KV x2 ----------------
// grid: 8 batches * 32 q-tiles * 2 kv-halves = 512 blocks, 256 thr.
__global__ __launch_bounds__(256) void attn_kernel(
    const __bf16* __restrict__ Qb, const __bf16* __restrict__ Kb,
    const __bf16* __restrict__ Vb, float* __restrict__ Opart,
    float* __restrict__ Ml)
{
  const int bid0 = blockIdx.x;
  const int bid = ((bid0 & 7) << 6) + (bid0 >> 3);   // one batch per XCD
  const int b = bid >> 6;
  const int qs = bid & 63;
  const int qt = qs >> 1;
  const int s  = qs & 1;
  const int q0 = qt * 64;
  const int half = (qt + 2) >> 1;
  const int kv_beg = s ? half : 0;
  const int kv_end = s ? (qt + 1) : half;
  const int nst = kv_end - kv_beg;

  const int t = threadIdx.x, lane = t & 63, w = t >> 6;
  const int hi = lane >> 4, lo = lane & 15;

  __shared__ __bf16 Ksm[2][64 * 128];   // [key][d], 256B rows, swizzled
  __shared__ __bf16 Vtsm[2][128 * 64];  // [d][key], 128B rows, swizzled
  __shared__ __bf16 Psm[4][16 * 64];    // per-wave P, swizzled

  v8bf aQ[4];
  {
    const __bf16* qp = Qb + ((size_t)(b * SEQ + q0 + w * 16 + lo)) * HD + hi * 8;
#pragma unroll
    for (int kk = 0; kk < 4; ++kk) aQ[kk] = *(const v8bf*)(qp + kk * 32);
  }

  const __bf16* kga[4];
#pragma unroll
  for (int i = 0; i < 4; ++i) {
    const int r = (w * 4 + i) * 4 + (lane >> 4);   // key row 0..63
    const int c = (lane & 15) ^ (r & 7);           // 16B chunk within 256B row
    kga[i] = Kb + ((size_t)(b * SEQ) + r) * HD + c * 8;
  }

  const int keyg = t >> 4, dg = t & 15;   // keys keyg*4.., d-cols dg*8..
  U8 vv[4];

  f32x4 accO[8];
  const f32x4 fz = {0.f, 0.f, 0.f, 0.f};
#pragma unroll
  for (int n = 0; n < 8; ++n) accO[n] = fz;
  float m_s[4], l_s[4];
#pragma unroll
  for (int r = 0; r < 4; ++r) { m_s[r] = -INFINITY; l_s[r] = 0.f; }

  const float scale = 0.022097086912079608f;  // 1/sqrt(2048)

  if (nst > 0) {
    auto STAGE_K = [&](int kv, int buf) {
      const size_t off = (size_t)kv * 64 * HD;
      char* kb = (char*)&Ksm[buf][0];
#pragma unroll
      for (int i = 0; i < 4; ++i) async16(kb + (w * 4 + i) * 1024, kga[i] + off);
    };
    auto LOAD_V = [&](int kv) {
      const __bf16* vp = Vb + ((size_t)(b * SEQ + kv * 64 + keyg * 4)) * HD + dg * 8;
#pragma unroll
      for (int j = 0; j < 4; ++j) vv[j].v = *(const v8bf*)(vp + (size_t)j * HD);
    };
    auto WRITE_VT = [&](int buf) {
      char* vb2 = (char*)&Vtsm[buf][0];
#pragma unroll
      for (int dd = 0; dd < 8; ++dd) {
        const int d = (dd + dg) & 7;               // rotation: row&7 spans lanes
        ushort4 pk = make_ushort4(vv[0].e[d], vv[1].e[d], vv[2].e[d], vv[3].e[d]);
        const int row = dg * 8 + d;
        *(ushort4*)(vb2 + row * 128 + ((keyg * 8) ^ ((row & 7) << 4))) = pk;
      }
    };

    STAGE_K(kv_beg, 0);
    LOAD_V(kv_beg);
    WRITE_VT(0);
    __syncthreads();   // K DMA drained + Vt visible

    for (int t2 = 0; t2 < nst; ++t2) {
      const int kv = kv_beg + t2;
      const int cur = t2 & 1;
      const bool more = (t2 + 1 < nst);
      if (more) { STAGE_K(kv + 1, cur ^ 1); LOAD_V(kv + 1); }

      // S = Q K^T
      f32x4 accS[4];
#pragma unroll
      for (int n = 0; n < 4; ++n) accS[n] = fz;
      const char* ksm = (const char*)&Ksm[cur][0];
#pragma unroll
      for (int kk = 0; kk < 4; ++kk) {
        const int cb = kk * 64 + hi * 16;
        v8bf bk[4];
#pragma unroll
        for (int n = 0; n < 4; ++n) {
          const int r = n * 16 + lo;
          bk[n] = *(const v8bf*)(ksm + r * 256 + (cb ^ ((r & 7) << 4)));
        }
#pragma unroll
        for (int n = 0; n < 4; ++n)
          accS[n] = __builtin_amdgcn_mfma_f32_16x16x32_bf16(aQ[kk], bk[n], accS[n], 0, 0, 0);
      }

      float sv[4][4];
      const bool diag = (kv == qt);
#pragma unroll
      for (int n = 0; n < 4; ++n)
#pragma unroll
        for (int r = 0; r < 4; ++r) {
          float v = accS[n][r] * scale;
          if (diag) {
            const int key = kv * 64 + n * 16 + lo;
            const int qr = q0 + w * 16 + hi * 4 + r;
            if (key > qr) v = -INFINITY;
          }
          sv[n][r] = v;
        }

      float mx[4];
#pragma unroll
      for (int r = 0; r < 4; ++r) {
        mx[r] = fmaxf(fmaxf(sv[0][r], sv[1][r]), fmaxf(sv[2][r], sv[3][r]));
#pragma unroll
        for (int off = 1; off < 16; off <<= 1)
          mx[r] = fmaxf(mx[r], __shfl_xor(mx[r], off));
      }
      float corr[4], p[4][4], rs[4];
#pragma unroll
      for (int r = 0; r < 4; ++r) {
        const float mnew = fmaxf(m_s[r], mx[r]);
        corr[r] = __expf(m_s[r] - mnew);
        m_s[r] = mnew;
        rs[r] = 0.f;
      }
#pragma unroll
      for (int n = 0; n < 4; ++n)
#pragma unroll
        for (int r = 0; r < 4; ++r) {
          p[n][r] = __expf(sv[n][r] - m_s[r]);
          rs[r] += p[n][r];
        }
#pragma unroll
      for (int r = 0; r < 4; ++r) {
#pragma unroll
        for (int off = 1; off < 16; off <<= 1) rs[r] += __shfl_xor(rs[r], off);
        l_s[r] = l_s[r] * corr[r] + rs[r];
      }
#pragma unroll
      for (int n = 0; n < 8; ++n)
#pragma unroll
        for (int r = 0; r < 4; ++r) accO[n][r] *= corr[r];

#pragma unroll
      for (int n = 0; n < 4; ++n)
#pragma unroll
        for (int r = 0; r < 4; ++r) {
          const int row = hi * 4 + r;
          __bf16 h = (__bf16)p[n][r];
          *(unsigned short*)((char*)&Psm[w][0] + row * 128 +
                             (((n * 16 + lo) * 2) ^ ((row & 7) << 4))) =
              __builtin_bit_cast(unsigned short, h);
        }

      if (more) WRITE_VT(cur ^ 1);

      const char* vsm = (const char*)&Vtsm[cur][0];
#pragma unroll
      for (int k2 = 0; k2 < 2; ++k2) {
        const int cb = k2 * 64 + hi * 16;
        const v8bf aP = *(const v8bf*)((const char*)&Psm[w][0] + lo * 128 + (cb ^ ((lo & 7) << 4)));
#pragma unroll
        for (int n = 0; n < 8; ++n) {
          const int r = n * 16 + lo;
          const v8bf bv = *(const v8bf*)(vsm + r * 128 + (cb ^ ((r & 7) << 4)));
          accO[n] = __builtin_amdgcn_mfma_f32_16x16x32_bf16(aP, bv, accO[n], 0, 0, 0);
        }
      }
      if (more) __syncthreads();
    }
  }

#pragma unroll
  for (int r = 0; r < 4; ++r) {
    const int qr = q0 + w * 16 + hi * 4 + r;
    float* op = Opart + ((size_t)s * NROWS + b * SEQ + qr) * HD + lo;
#pragma unroll
    for (int n = 0; n < 8; ++n) op[n * 16] = accO[n][r];
    if (lo == 0) {
      float* mlp = Ml + ((size_t)s * NROWS + b * SEQ + qr) * 2;
      mlp[0] = m_s[r];
      mlp[1] = l_s[r];
    }
  }
}

// ---------------- combine the two KV-half partials ----------------
__global__ __launch_bounds__(256) void combine_kernel(
    const float* __restrict__ Opart, const float* __restrict__ Ml,
    float* __restrict__ out)
{
  const int idx = blockIdx.x * 256 + threadIdx.x;  // 0..32767
  const int row = idx >> 1, h = idx & 1;
  const float m0 = Ml[(size_t)row * 2],           l0 = Ml[(size_t)row * 2 + 1];
  const float m1 = Ml[((size_t)NROWS + row) * 2], l1 = Ml[((size_t)NROWS + row) * 2 + 1];
  const float M = fmaxf(m0, m1);
  const float e0 = __expf(m0 - M), e1 = __expf(m1 - M);
  const float inv = 1.f / (l0 * e0 + l1 * e1);
  const float4* p0 = (const float4*)(Opart + (size_t)row * HD + h * 64);
  const float4* p1 = (const float4*)(Opart + ((size_t)NROWS + row) * HD + h * 64);
  float4* po = (float4*)(out + (size_t)row * HD + h * 64);
#pragma unroll
  for (int j = 0; j < 16; ++j) {
    float4 a = p0[j], c = p1[j];
    float4 r;
    r.x = (a.x * e0 + c.x * e1) * inv;
    r.y = (a.y * e0 + c.y * e1) * inv;
    r.z = (a.z * e0 + c.z * e1) * inv;
    r.w = (a.w * e0 + c.w * e1) * inv;
    po[j] = r;
  }
}

extern "C" void kernel_launch(void* const* d_in, const int* in_sizes, int n_in,
                              void* d_out, int out_size, void* d_ws, size_t ws_size,
                              hipStream_t stream) {
  const float* x  = (const float*)d_in[0];
  const float* Wq = (const float*)d_in[1];
  const float* bq = (const float*)d_in[2];
  const float* Wk = (const float*)d_in[3];
  const float* bk = (const float*)d_in[4];
  const float* Wv = (const float*)d_in[5];
  const float* bv = (const float*)d_in[6];
  float* out = (float*)d_out;

  // workspace layout (~30 MiB)
  __bf16* Qb = (__bf16*)d_ws;                        // 16384x128 bf16 each
  __bf16* Kb = Qb + (size_t)NROWS * HD;
  __bf16* Vb = Kb + (size_t)NROWS * HD;
  __bf16* Wb = Vb + (size_t)NROWS * HD;              // 3 x 128 x 2048 bf16
  float*  Opart = (float*)(Wb + (size_t)3 * HD * NEMB);  // 2 x 16384 x 128 fp32
  float*  Ml    = Opart + (size_t)2 * NROWS * HD;        // 2 x 16384 x 2 fp32

  wconv_kernel<<<dim3(3 * 64), dim3(256), 0, stream>>>(Wq, Wk, Wv, Wb);
  qkv_proj_kernel<<<dim3(256 * 3), dim3(512), 0, stream>>>(
      x, Wb, bq, bk, bv, Qb, Kb, Vb);
  attn_kernel<<<dim3(BATCH * 32 * 2), dim3(256), 0, stream>>>(Qb, Kb, Vb, Opart, Ml);
  combine_kernel<<<dim3(NROWS * 2 / 256), dim3(256), 0, stream>>>(Opart, Ml, out);
}

// Round 12
// 116.715 us; speedup vs baseline: 1.1631x; 1.1631x over previous
//
#include <hip/hip_runtime.h>
#include <cmath>

#define BATCH 8
#define SEQ   2048
#define NEMB  2048
#define HD    128
#define NROWS (BATCH * SEQ)   // 16384

typedef __bf16 v8bf __attribute__((ext_vector_type(8)));
typedef float  f32x4 __attribute__((ext_vector_type(4)));

union U8 { v8bf v; __bf16 b[8]; unsigned short e[8]; };

__device__ inline void async16(void* lds, const void* g) {
  __builtin_amdgcn_global_load_lds(
      (const __attribute__((address_space(1))) unsigned int*)g,
      (__attribute__((address_space(3))) unsigned int*)lds, 16, 0, 0);
}

__device__ inline v8bf cvt8(float4 a, float4 b) {
  U8 u;
  u.b[0] = (__bf16)a.x; u.b[1] = (__bf16)a.y; u.b[2] = (__bf16)a.z; u.b[3] = (__bf16)a.w;
  u.b[4] = (__bf16)b.x; u.b[5] = (__bf16)b.y; u.b[6] = (__bf16)b.z; u.b[7] = (__bf16)b.w;
  return u.v;
}

// ---------------- W fp32 -> bf16 (3 x 128 x 2048) ----------------
__global__ __launch_bounds__(256) void wconv_kernel(
    const float* __restrict__ Wq, const float* __restrict__ Wk,
    const float* __restrict__ Wv, __bf16* __restrict__ out) {
  const int id = blockIdx.x;                 // 3 * 64 blocks
  const int proj = id >> 6, blk = id & 63;
  const float* __restrict__ W = proj == 0 ? Wq : proj == 1 ? Wk : Wv;
  __bf16* __restrict__ o = out + (size_t)proj * (HD * NEMB);
  const int base = blk * 4096 + threadIdx.x * 16;
  const float4* s = (const float4*)(W + base);
  float4 f0 = s[0], f1 = s[1], f2 = s[2], f3 = s[3];
  *(v8bf*)(o + base) = cvt8(f0, f1);
  *(v8bf*)(o + base + 8) = cvt8(f2, f3);
}

// ---------------- QKV projection: BK=128, 16 windows ----------------
// Mtile=64, Ntile=128, 4 waves (2x2 of 32x64). Per K-step (128):
//   A bf16 [64][128] (16 KB): coalesced reg loads (4 segs x 512B/instr),
//     cvt, 4x ds_write_b128 (XOR-swizzled). ALOAD(t+1) issued after b2 ->
//     drains free at next b1 (covered by 32-MFMA compute).
//   B bf16 [128][128] (32 KB) via global_load_lds (inverse-swz source).
// LDS 48 KB -> 3 blocks/CU; grid 768 -> 16 serial windows/CU (vs r7's 32).
__global__ __launch_bounds__(256, 3) void qkv_proj_kernel(
    const float* __restrict__ x, const __bf16* __restrict__ Wb,
    const float* __restrict__ bq, const float* __restrict__ bk,
    const float* __restrict__ bv,
    __bf16* __restrict__ Qb, __bf16* __restrict__ Kb, __bf16* __restrict__ Vb)
{
  const int bid0 = blockIdx.x;
  const int bid = ((bid0 & 7) * 96) + (bid0 >> 3);   // 768 % 8 == 0
  const int mt = bid / 3;
  const int proj = bid % 3;
  const __bf16* __restrict__ W = Wb + (size_t)proj * (HD * NEMB);
  const float* __restrict__ bias = proj == 0 ? bq : proj == 1 ? bk : bv;
  __bf16* __restrict__ Out = proj == 0 ? Qb : proj == 1 ? Kb : Vb;
  const int m0 = mt * 64;

  __shared__ __bf16 Asm[64 * 128];    // 16 KB, 256B rows, 16B-chunk XOR swz
  __shared__ __bf16 Bsm[128 * 128];   // 32 KB, 256B rows, same swz

  const int t = threadIdx.x, lane = t & 63, w = t >> 6;
  const int wm = w >> 1, wn = w & 1;
  const int hi = lane >> 4, lo = lane & 15;

  // A: 4 chunk-groups/wave; lane covers (row = (w*4+i)*4 + lane>>4, piece = lane&15)
  const float* pa[4];
  int aw[4];
#pragma unroll
  for (int i = 0; i < 4; ++i) {
    const int r = (w * 4 + i) * 4 + (lane >> 4);
    const int p = lane & 15;
    pa[i] = x + (size_t)(m0 + r) * NEMB + p * 8;
    aw[i] = r * 256 + ((p ^ (r & 7)) << 4);
  }
  // B: 8 chunks/wave via DMA (linear dest, inverse-swizzled source)
  const __bf16* pb[8];
  char* lb[8];
#pragma unroll
  for (int i = 0; i < 8; ++i) {
    const int j = w * 8 + i;
    const int r = j * 4 + (lane >> 4);
    const int c = (lane & 15) ^ (r & 7);
    pb[i] = W + (size_t)r * NEMB + c * 8;
    lb[i] = (char*)Bsm + j * 1024;
  }

  f32x4 acc[2][4];
  const f32x4 fz = {0.f, 0.f, 0.f, 0.f};
#pragma unroll
  for (int m = 0; m < 2; ++m)
#pragma unroll
    for (int n = 0; n < 4; ++n) acc[m][n] = fz;

  float4 fa[4][2];
  auto ALOAD = [&](int tt) {
#pragma unroll
    for (int i = 0; i < 4; ++i) {
      const float* p = pa[i] + tt * 128;
      fa[i][0] = *(const float4*)(p);
      fa[i][1] = *(const float4*)(p + 4);
    }
  };
  auto AWRITE = [&]() {
#pragma unroll
    for (int i = 0; i < 4; ++i)
      *(v8bf*)((char*)Asm + aw[i]) = cvt8(fa[i][0], fa[i][1]);
  };
  auto STAGE_B = [&](int tt) {
#pragma unroll
    for (int i = 0; i < 8; ++i) async16(lb[i], pb[i] + tt * 128);
  };

  const int NT = NEMB / 128;  // 16
  ALOAD(0);
  for (int tt = 0; tt < NT; ++tt) {
    __syncthreads();   // compute(tt-1) done; drains ALOAD(tt) (covered by it)
    STAGE_B(tt);
    AWRITE();
    __syncthreads();   // B DMA drained + A visible
    if (tt + 1 < NT) ALOAD(tt + 1);   // flies under COMPUTE

#pragma unroll
    for (int kk = 0; kk < 4; ++kk) {
      const int kc = kk * 4 + hi;      // 16B chunk 0..15
      v8bf a[2], b[4];
#pragma unroll
      for (int m = 0; m < 2; ++m) {
        const int r = wm * 32 + m * 16 + lo;
        a[m] = *(const v8bf*)((const char*)Asm + r * 256 + ((kc ^ (r & 7)) << 4));
      }
#pragma unroll
      for (int n = 0; n < 4; ++n) {
        const int r = wn * 64 + n * 16 + lo;
        b[n] = *(const v8bf*)((const char*)Bsm + r * 256 + ((kc ^ (r & 7)) << 4));
      }
#pragma unroll
      for (int m = 0; m < 2; ++m)
#pragma unroll
        for (int n = 0; n < 4; ++n)
          acc[m][n] = __builtin_amdgcn_mfma_f32_16x16x32_bf16(a[m], b[n], acc[m][n], 0, 0, 0);
    }
  }

#pragma unroll
  for (int n = 0; n < 4; ++n) {
    const int col = wn * 64 + n * 16 + lo;
    const float bi = bias[col];
#pragma unroll
    for (int m = 0; m < 2; ++m) {
#pragma unroll
      for (int r = 0; r < 4; ++r) {
        const int row = m0 + wm * 32 + m * 16 + hi * 4 + r;
        Out[(size_t)row * HD + col] = (__bf16)(acc[m][n][r] + bi);
      }
    }
  }
}

// ---------------- Flash attention, split-KV x4 ----------------
// grid: 8 batches * 32 q-tiles * 4 kv-chunks = 1024 blocks, 256 thr.
// Writes unnormalized O (bf16) + (m,l); combine_kernel merges 4 ways.
__global__ __launch_bounds__(256) void attn_kernel(
    const __bf16* __restrict__ Qb, const __bf16* __restrict__ Kb,
    const __bf16* __restrict__ Vb, __bf16* __restrict__ Opart,
    float* __restrict__ Ml)
{
  const int bid0 = blockIdx.x;
  const int bid = ((bid0 & 7) << 7) + (bid0 >> 3);   // one batch per XCD
  const int b = bid >> 7;
  const int q = bid & 127;
  const int qt = q >> 2;
  const int s  = q & 3;
  const int q0 = qt * 64;
  const int kv_beg = (s * (qt + 1)) >> 2;
  const int kv_end = ((s + 1) * (qt + 1)) >> 2;
  const int nst = kv_end - kv_beg;

  const int t = threadIdx.x, lane = t & 63, w = t >> 6;
  const int hi = lane >> 4, lo = lane & 15;

  __shared__ __bf16 Ksm[2][64 * 128];   // [key][d], 256B rows, swizzled
  __shared__ __bf16 Vtsm[2][128 * 64];  // [d][key], 128B rows, swizzled
  __shared__ __bf16 Psm[4][16 * 64];    // per-wave P, swizzled

  v8bf aQ[4];
  {
    const __bf16* qp = Qb + ((size_t)(b * SEQ + q0 + w * 16 + lo)) * HD + hi * 8;
#pragma unroll
    for (int kk = 0; kk < 4; ++kk) aQ[kk] = *(const v8bf*)(qp + kk * 32);
  }

  const __bf16* kga[4];
#pragma unroll
  for (int i = 0; i < 4; ++i) {
    const int r = (w * 4 + i) * 4 + (lane >> 4);   // key row 0..63
    const int c = (lane & 15) ^ (r & 7);           // 16B chunk within 256B row
    kga[i] = Kb + ((size_t)(b * SEQ) + r) * HD + c * 8;
  }

  const int keyg = t >> 4, dg = t & 15;   // keys keyg*4.., d-cols dg*8..
  U8 vv[4];

  f32x4 accO[8];
  const f32x4 fz = {0.f, 0.f, 0.f, 0.f};
#pragma unroll
  for (int n = 0; n < 8; ++n) accO[n] = fz;
  float m_s[4], l_s[4];
#pragma unroll
  for (int r = 0; r < 4; ++r) { m_s[r] = -INFINITY; l_s[r] = 0.f; }

  const float scale = 0.022097086912079608f;  // 1/sqrt(2048)

  if (nst > 0) {
    auto STAGE_K = [&](int kv, int buf) {
      const size_t off = (size_t)kv * 64 * HD;
      char* kb = (char*)&Ksm[buf][0];
#pragma unroll
      for (int i = 0; i < 4; ++i) async16(kb + (w * 4 + i) * 1024, kga[i] + off);
    };
    auto LOAD_V = [&](int kv) {
      const __bf16* vp = Vb + ((size_t)(b * SEQ + kv * 64 + keyg * 4)) * HD + dg * 8;
#pragma unroll
      for (int j = 0; j < 4; ++j) vv[j].v = *(const v8bf*)(vp + (size_t)j * HD);
    };
    auto WRITE_VT = [&](int buf) {
      char* vb2 = (char*)&Vtsm[buf][0];
#pragma unroll
      for (int dd = 0; dd < 8; ++dd) {
        const int d = (dd + dg) & 7;               // rotation: row&7 spans lanes
        ushort4 pk = make_ushort4(vv[0].e[d], vv[1].e[d], vv[2].e[d], vv[3].e[d]);
        const int row = dg * 8 + d;
        *(ushort4*)(vb2 + row * 128 + ((keyg * 8) ^ ((row & 7) << 4))) = pk;
      }
    };

    STAGE_K(kv_beg, 0);
    LOAD_V(kv_beg);
    WRITE_VT(0);
    __syncthreads();   // K DMA drained + Vt visible

    for (int t2 = 0; t2 < nst; ++t2) {
      const int kv = kv_beg + t2;
      const int cur = t2 & 1;
      const bool more = (t2 + 1 < nst);
      if (more) { STAGE_K(kv + 1, cur ^ 1); LOAD_V(kv + 1); }

      // S = Q K^T
      f32x4 accS[4];
#pragma unroll
      for (int n = 0; n < 4; ++n) accS[n] = fz;
      const char* ksm = (const char*)&Ksm[cur][0];
#pragma unroll
      for (int kk = 0; kk < 4; ++kk) {
        const int cb = kk * 64 + hi * 16;
        v8bf bk[4];
#pragma unroll
        for (int n = 0; n < 4; ++n) {
          const int r = n * 16 + lo;
          bk[n] = *(const v8bf*)(ksm + r * 256 + (cb ^ ((r & 7) << 4)));
        }
#pragma unroll
        for (int n = 0; n < 4; ++n)
          accS[n] = __builtin_amdgcn_mfma_f32_16x16x32_bf16(aQ[kk], bk[n], accS[n], 0, 0, 0);
      }

      float sv[4][4];
      const bool diag = (kv == qt);
#pragma unroll
      for (int n = 0; n < 4; ++n)
#pragma unroll
        for (int r = 0; r < 4; ++r) {
          float v = accS[n][r] * scale;
          if (diag) {
            const int key = kv * 64 + n * 16 + lo;
            const int qr = q0 + w * 16 + hi * 4 + r;
            if (key > qr) v = -INFINITY;
          }
          sv[n][r] = v;
        }

      float mx[4];
#pragma unroll
      for (int r = 0; r < 4; ++r) {
        mx[r] = fmaxf(fmaxf(sv[0][r], sv[1][r]), fmaxf(sv[2][r], sv[3][r]));
#pragma unroll
        for (int off = 1; off < 16; off <<= 1)
          mx[r] = fmaxf(mx[r], __shfl_xor(mx[r], off));
      }
      float corr[4], p[4][4], rs[4];
#pragma unroll
      for (int r = 0; r < 4; ++r) {
        const float mnew = fmaxf(m_s[r], mx[r]);
        corr[r] = __expf(m_s[r] - mnew);
        m_s[r] = mnew;
        rs[r] = 0.f;
      }
#pragma unroll
      for (int n = 0; n < 4; ++n)
#pragma unroll
        for (int r = 0; r < 4; ++r) {
          p[n][r] = __expf(sv[n][r] - m_s[r]);
          rs[r] += p[n][r];
        }
#pragma unroll
      for (int r = 0; r < 4; ++r) {
#pragma unroll
        for (int off = 1; off < 16; off <<= 1) rs[r] += __shfl_xor(rs[r], off);
        l_s[r] = l_s[r] * corr[r] + rs[r];
      }
#pragma unroll
      for (int n = 0; n < 8; ++n)
#pragma unroll
        for (int r = 0; r < 4; ++r) accO[n][r] *= corr[r];

#pragma unroll
      for (int n = 0; n < 4; ++n)
#pragma unroll
        for (int r = 0; r < 4; ++r) {
          const int row = hi * 4 + r;
          __bf16 h = (__bf16)p[n][r];
          *(unsigned short*)((char*)&Psm[w][0] + row * 128 +
                             (((n * 16 + lo) * 2) ^ ((row & 7) << 4))) =
              __builtin_bit_cast(unsigned short, h);
        }

      if (more) WRITE_VT(cur ^ 1);

      const char* vsm = (const char*)&Vtsm[cur][0];
#pragma unroll
      for (int k2 = 0; k2 < 2; ++k2) {
        const int cb = k2 * 64 + hi * 16;
        const v8bf aP = *(const v8bf*)((const char*)&Psm[w][0] + lo * 128 + (cb ^ ((lo & 7) << 4)));
#pragma unroll
        for (int n = 0; n < 8; ++n) {
          const int r = n * 16 + lo;
          const v8bf bv = *(const v8bf*)(vsm + r * 128 + (cb ^ ((r & 7) << 4)));
          accO[n] = __builtin_amdgcn_mfma_f32_16x16x32_bf16(aP, bv, accO[n], 0, 0, 0);
        }
      }
      if (more) __syncthreads();
    }
  }

  // store partials: unnormalized O (bf16), m, l
#pragma unroll
  for (int r = 0; r < 4; ++r) {
    const int qr = q0 + w * 16 + hi * 4 + r;
    __bf16* op = Opart + ((size_t)s * NROWS + b * SEQ + qr) * HD + lo;
#pragma unroll
    for (int n = 0; n < 8; ++n) op[n * 16] = (__bf16)accO[n][r];
    if (lo == 0) {
      float* mlp = Ml + ((size_t)s * NROWS + b * SEQ + qr) * 2;
      mlp[0] = m_s[r];
      mlp[1] = l_s[r];
    }
  }
}

// ---------------- combine the four KV-chunk partials ----------------
__global__ __launch_bounds__(256) void combine_kernel(
    const __bf16* __restrict__ Opart, const float* __restrict__ Ml,
    float* __restrict__ out)
{
  const int idx = blockIdx.x * 256 + threadIdx.x;  // 0..65535
  const int row = idx >> 2, ch = idx & 3;          // 32-col chunk
  float m[4], l[4];
#pragma unroll
  for (int s = 0; s < 4; ++s) {
    const float* mlp = Ml + ((size_t)s * NROWS + row) * 2;
    m[s] = mlp[0];
    l[s] = mlp[1];
  }
  const float M = fmaxf(fmaxf(m[0], m[1]), fmaxf(m[2], m[3]));
  float e[4], denom = 0.f;
#pragma unroll
  for (int s = 0; s < 4; ++s) { e[s] = __expf(m[s] - M); denom += l[s] * e[s]; }
  const float inv = 1.f / denom;

  float* po = out + (size_t)row * HD + ch * 32;
#pragma unroll
  for (int j = 0; j < 4; ++j) {     // 4 groups of 8 cols
    float sum[8];
#pragma unroll
    for (int q2 = 0; q2 < 8; ++q2) sum[q2] = 0.f;
#pragma unroll
    for (int s = 0; s < 4; ++s) {
      U8 o;
      o.v = *(const v8bf*)(Opart + ((size_t)s * NROWS + row) * HD + ch * 32 + j * 8);
#pragma unroll
      for (int q2 = 0; q2 < 8; ++q2) sum[q2] += (float)o.b[q2] * e[s];
    }
#pragma unroll
    for (int q2 = 0; q2 < 8; ++q2) po[j * 8 + q2] = sum[q2] * inv;
  }
}

extern "C" void kernel_launch(void* const* d_in, const int* in_sizes, int n_in,
                              void* d_out, int out_size, void* d_ws, size_t ws_size,
                              hipStream_t stream) {
  const float* x  = (const float*)d_in[0];
  const float* Wq = (const float*)d_in[1];
  const float* bq = (const float*)d_in[2];
  const float* Wk = (const float*)d_in[3];
  const float* bk = (const float*)d_in[4];
  const float* Wv = (const float*)d_in[5];
  const float* bv = (const float*)d_in[6];
  float* out = (float*)d_out;

  // workspace (~30 MiB)
  __bf16* Qb = (__bf16*)d_ws;                        // 16384x128 bf16 each
  __bf16* Kb = Qb + (size_t)NROWS * HD;
  __bf16* Vb = Kb + (size_t)NROWS * HD;
  __bf16* Wb = Vb + (size_t)NROWS * HD;              // 3 x 128 x 2048 bf16
  __bf16* Opart = Wb + (size_t)3 * HD * NEMB;        // 4 x 16384 x 128 bf16
  float*  Ml = (float*)(Opart + (size_t)4 * NROWS * HD);  // 4 x 16384 x 2 fp32

  wconv_kernel<<<dim3(3 * 64), dim3(256), 0, stream>>>(Wq, Wk, Wv, Wb);
  qkv_proj_kernel<<<dim3(256 * 3), dim3(256), 0, stream>>>(
      x, Wb, bq, bk, bv, Qb, Kb, Vb);
  attn_kernel<<<dim3(BATCH * 32 * 4), dim3(256), 0, stream>>>(Qb, Kb, Vb, Opart, Ml);
  combine_kernel<<<dim3(NROWS * 4 / 256), dim3(256), 0, stream>>>(Opart, Ml, out);
}

// Round 13
// 111.190 us; speedup vs baseline: 1.2209x; 1.0497x over previous
//
#include <hip/hip_runtime.h>
#include <cmath>

#define BATCH 8
#define SEQ   2048
#define NEMB  2048
#define HD    128
#define NROWS (BATCH * SEQ)   // 16384

typedef __bf16 v8bf __attribute__((ext_vector_type(8)));
typedef float  f32x4 __attribute__((ext_vector_type(4)));

union U8 { v8bf v; __bf16 b[8]; unsigned short e[8]; };
union F4 { f32x4 v; float f[4]; };

__device__ inline void async16(void* lds, const void* g) {
  __builtin_amdgcn_global_load_lds(
      (const __attribute__((address_space(1))) unsigned int*)g,
      (__attribute__((address_space(3))) unsigned int*)lds, 16, 0, 0);
}

__device__ inline v8bf cvt8(float4 a, float4 b) {
  U8 u;
  u.b[0] = (__bf16)a.x; u.b[1] = (__bf16)a.y; u.b[2] = (__bf16)a.z; u.b[3] = (__bf16)a.w;
  u.b[4] = (__bf16)b.x; u.b[5] = (__bf16)b.y; u.b[6] = (__bf16)b.z; u.b[7] = (__bf16)b.w;
  return u.v;
}

// ---------------- W fp32 -> bf16 (3 x 128 x 2048) ----------------
__global__ __launch_bounds__(256) void wconv_kernel(
    const float* __restrict__ Wq, const float* __restrict__ Wk,
    const float* __restrict__ Wv, __bf16* __restrict__ out) {
  const int id = blockIdx.x;                 // 3 * 64 blocks
  const int proj = id >> 6, blk = id & 63;
  const float* __restrict__ W = proj == 0 ? Wq : proj == 1 ? Wk : Wv;
  __bf16* __restrict__ o = out + (size_t)proj * (HD * NEMB);
  const int base = blk * 4096 + threadIdx.x * 16;
  const float4* s = (const float4*)(W + base);
  float4 f0 = s[0], f1 = s[1], f2 = s[2], f3 = s[3];
  *(v8bf*)(o + base) = cvt8(f0, f1);
  *(v8bf*)(o + base + 8) = cvt8(f2, f3);
}

// ---------------- Fused QKV projection ----------------
// One block per 64-row x-panel computes ALL THREE projections (64x384 out).
// 512 thr / 8 waves (2m x 4n); wave owns 32x96 (2x6 frags).
// LDS 128 KB: A fp32 [64][64] x2 (32K) + B bf16 [384][64] x2 (96K), both DMA.
// T3/T4 loop: barrier; STAGE(t+1, other buf); vmcnt(8) [counted]; barrier;
// COMPUTE(t). No vmcnt(0) in the loop -> DMA latency hidden under compute.
__global__ __launch_bounds__(512) void qkv_fused_kernel(
    const float* __restrict__ x, const __bf16* __restrict__ Wb,
    const float* __restrict__ bq, const float* __restrict__ bk,
    const float* __restrict__ bv,
    __bf16* __restrict__ Qb, __bf16* __restrict__ Kb, __bf16* __restrict__ Vb)
{
  const int bid0 = blockIdx.x;
  const int mt = ((bid0 & 7) << 5) + (bid0 >> 3);   // 256 % 8 == 0, chunk 32
  const int m0 = mt * 64;

  __shared__ char smem[131072];
  char* const A0 = smem;               // 16 KB
  char* const A1 = smem + 16384;       // 16 KB
  char* const Bu0 = smem + 32768;      // 48 KB
  char* const Bu1 = smem + 81920;      // 48 KB

  const int t = threadIdx.x, lane = t & 63, w = t >> 6;
  const int wm = w >> 2, wn4 = w & 3;       // wave: rows wm*32.., cols wn4*96..
  const int hi = lane >> 4, lo = lane & 15;

  // A staging: 16 chunks of 1KB (4 rows x 256B); 2 chunks/wave
  const float* pa[2];
  int laOff[2];
#pragma unroll
  for (int i = 0; i < 2; ++i) {
    const int j = w * 2 + i;
    const int r = j * 4 + (lane >> 4);
    const int c = (lane & 15) ^ (r & 7);
    pa[i] = x + (size_t)(m0 + r) * NEMB + c * 4;
    laOff[i] = j * 1024;
  }
  // B staging: 48 chunks of 1KB (8 rows x 128B); 6 chunks/wave; rows 0..383
  const __bf16* pb[6];
  int lbOff[6];
#pragma unroll
  for (int i = 0; i < 6; ++i) {
    const int j = w * 6 + i;
    const int r = j * 8 + (lane >> 3);       // 0..383
    const int pj = r >> 7, wr = r & 127;
    const int c = (lane & 7) ^ (r & 7);
    pb[i] = Wb + (size_t)pj * (HD * NEMB) + (size_t)wr * NEMB + c * 8;
    lbOff[i] = j * 1024;
  }

  f32x4 acc[2][6];
  const f32x4 fz = {0.f, 0.f, 0.f, 0.f};
#pragma unroll
  for (int m = 0; m < 2; ++m)
#pragma unroll
    for (int n = 0; n < 6; ++n) acc[m][n] = fz;

  auto STAGE = [&](int tt, char* Ab, char* Bb) {
    const int k0 = tt * 64;
#pragma unroll
    for (int i = 0; i < 2; ++i) async16(Ab + laOff[i], pa[i] + k0);
#pragma unroll
    for (int i = 0; i < 6; ++i) async16(Bb + lbOff[i], pb[i] + k0);
  };
  auto COMPUTE = [&](const char* Ab, const char* Bb) {
#pragma unroll
    for (int kk = 0; kk < 2; ++kk) {
      v8bf a[2], b[6];
#pragma unroll
      for (int m = 0; m < 2; ++m) {
        const int r = wm * 32 + m * 16 + lo;
        const int s = kk * 8 + hi * 2;
        const char* rowp = Ab + r * 256;
        F4 a0, a1;
        a0.v = *(const f32x4*)(rowp + (((s)     ^ (r & 7)) << 4));
        a1.v = *(const f32x4*)(rowp + (((s + 1) ^ (r & 7)) << 4));
        U8 u;
#pragma unroll
        for (int q = 0; q < 4; ++q) {
          u.b[q]     = (__bf16)a0.f[q];
          u.b[q + 4] = (__bf16)a1.f[q];
        }
        a[m] = u.v;
      }
      const int kc = kk * 4 + hi;
#pragma unroll
      for (int n = 0; n < 6; ++n) {
        const int r = wn4 * 96 + n * 16 + lo;
        b[n] = *(const v8bf*)(Bb + r * 128 + ((kc ^ (r & 7)) << 4));
      }
#pragma unroll
      for (int m = 0; m < 2; ++m)
#pragma unroll
        for (int n = 0; n < 6; ++n)
          acc[m][n] = __builtin_amdgcn_mfma_f32_16x16x32_bf16(a[m], b[n], acc[m][n], 0, 0, 0);
    }
  };

  const int NT = NEMB / 64;  // 32 (even)
  STAGE(0, A0, Bu0);
  for (int tt = 0; tt < NT; tt += 2) {
    // step tt: compute buf0, prefetch tt+1 -> buf1
    __builtin_amdgcn_s_barrier();           // compute(tt-1) [buf1] done everywhere
    STAGE(tt + 1, A1, Bu1);
    asm volatile("s_waitcnt vmcnt(8)" ::: "memory");  // own step-tt DMAs done
    __builtin_amdgcn_s_barrier();           // all waves' step-tt data resident
    COMPUTE(A0, Bu0);
    // step tt+1: compute buf1, prefetch tt+2 -> buf0
    __builtin_amdgcn_s_barrier();
    if (tt + 2 < NT) {
      STAGE(tt + 2, A0, Bu0);
      asm volatile("s_waitcnt vmcnt(8)" ::: "memory");
    } else {
      asm volatile("s_waitcnt vmcnt(0)" ::: "memory");
    }
    __builtin_amdgcn_s_barrier();
    COMPUTE(A1, Bu1);
  }

  // epilogue: per-frag projection select (16-row frags never cross proj edge)
#pragma unroll
  for (int n = 0; n < 6; ++n) {
    const int rrb = wn4 * 96 + n * 16;      // 0..368, multiple of 16
    const int pj = rrb >> 7;
    const int col = (rrb & 127) + lo;
    __bf16* __restrict__ Out = pj == 0 ? Qb : pj == 1 ? Kb : Vb;
    const float* __restrict__ bias = pj == 0 ? bq : pj == 1 ? bk : bv;
    const float bi = bias[col];
#pragma unroll
    for (int m = 0; m < 2; ++m) {
#pragma unroll
      for (int r = 0; r < 4; ++r) {
        const int row = m0 + wm * 32 + m * 16 + hi * 4 + r;
        Out[(size_t)row * HD + col] = (__bf16)(acc[m][n][r] + bi);
      }
    }
  }
}

// ---------------- Flash attention, split-KV x4 ----------------
// grid: 8 batches * 32 q-tiles * 4 kv-chunks = 1024 blocks, 256 thr.
__global__ __launch_bounds__(256) void attn_kernel(
    const __bf16* __restrict__ Qb, const __bf16* __restrict__ Kb,
    const __bf16* __restrict__ Vb, __bf16* __restrict__ Opart,
    float* __restrict__ Ml)
{
  const int bid0 = blockIdx.x;
  const int bid = ((bid0 & 7) << 7) + (bid0 >> 3);   // one batch per XCD
  const int b = bid >> 7;
  const int q = bid & 127;
  const int qt = q >> 2;
  const int s  = q & 3;
  const int q0 = qt * 64;
  const int kv_beg = (s * (qt + 1)) >> 2;
  const int kv_end = ((s + 1) * (qt + 1)) >> 2;
  const int nst = kv_end - kv_beg;

  const int t = threadIdx.x, lane = t & 63, w = t >> 6;
  const int hi = lane >> 4, lo = lane & 15;

  __shared__ __bf16 Ksm[2][64 * 128];   // [key][d], 256B rows, swizzled
  __shared__ __bf16 Vtsm[2][128 * 64];  // [d][key], 128B rows, swizzled
  __shared__ __bf16 Psm[4][16 * 64];    // per-wave P, swizzled

  v8bf aQ[4];
  {
    const __bf16* qp = Qb + ((size_t)(b * SEQ + q0 + w * 16 + lo)) * HD + hi * 8;
#pragma unroll
    for (int kk = 0; kk < 4; ++kk) aQ[kk] = *(const v8bf*)(qp + kk * 32);
  }

  const __bf16* kga[4];
#pragma unroll
  for (int i = 0; i < 4; ++i) {
    const int r = (w * 4 + i) * 4 + (lane >> 4);   // key row 0..63
    const int c = (lane & 15) ^ (r & 7);           // 16B chunk within 256B row
    kga[i] = Kb + ((size_t)(b * SEQ) + r) * HD + c * 8;
  }

  const int keyg = t >> 4, dg = t & 15;   // keys keyg*4.., d-cols dg*8..
  U8 vv[4];

  f32x4 accO[8];
  const f32x4 fz = {0.f, 0.f, 0.f, 0.f};
#pragma unroll
  for (int n = 0; n < 8; ++n) accO[n] = fz;
  float m_s[4], l_s[4];
#pragma unroll
  for (int r = 0; r < 4; ++r) { m_s[r] = -INFINITY; l_s[r] = 0.f; }

  const float scale = 0.022097086912079608f;  // 1/sqrt(2048)

  if (nst > 0) {
    auto STAGE_K = [&](int kv, int buf) {
      const size_t off = (size_t)kv * 64 * HD;
      char* kb = (char*)&Ksm[buf][0];
#pragma unroll
      for (int i = 0; i < 4; ++i) async16(kb + (w * 4 + i) * 1024, kga[i] + off);
    };
    auto LOAD_V = [&](int kv) {
      const __bf16* vp = Vb + ((size_t)(b * SEQ + kv * 64 + keyg * 4)) * HD + dg * 8;
#pragma unroll
      for (int j = 0; j < 4; ++j) vv[j].v = *(const v8bf*)(vp + (size_t)j * HD);
    };
    auto WRITE_VT = [&](int buf) {
      char* vb2 = (char*)&Vtsm[buf][0];
#pragma unroll
      for (int dd = 0; dd < 8; ++dd) {
        const int d = (dd + dg) & 7;               // rotation: row&7 spans lanes
        ushort4 pk = make_ushort4(vv[0].e[d], vv[1].e[d], vv[2].e[d], vv[3].e[d]);
        const int row = dg * 8 + d;
        *(ushort4*)(vb2 + row * 128 + ((keyg * 8) ^ ((row & 7) << 4))) = pk;
      }
    };

    STAGE_K(kv_beg, 0);
    LOAD_V(kv_beg);
    WRITE_VT(0);
    __syncthreads();   // K DMA drained + Vt visible

    for (int t2 = 0; t2 < nst; ++t2) {
      const int kv = kv_beg + t2;
      const int cur = t2 & 1;
      const bool more = (t2 + 1 < nst);
      if (more) { STAGE_K(kv + 1, cur ^ 1); LOAD_V(kv + 1); }

      // S = Q K^T
      f32x4 accS[4];
#pragma unroll
      for (int n = 0; n < 4; ++n) accS[n] = fz;
      const char* ksm = (const char*)&Ksm[cur][0];
#pragma unroll
      for (int kk = 0; kk < 4; ++kk) {
        const int cb = kk * 64 + hi * 16;
        v8bf bk[4];
#pragma unroll
        for (int n = 0; n < 4; ++n) {
          const int r = n * 16 + lo;
          bk[n] = *(const v8bf*)(ksm + r * 256 + (cb ^ ((r & 7) << 4)));
        }
#pragma unroll
        for (int n = 0; n < 4; ++n)
          accS[n] = __builtin_amdgcn_mfma_f32_16x16x32_bf16(aQ[kk], bk[n], accS[n], 0, 0, 0);
      }

      float sv[4][4];
      const bool diag = (kv == qt);
#pragma unroll
      for (int n = 0; n < 4; ++n)
#pragma unroll
        for (int r = 0; r < 4; ++r) {
          float v = accS[n][r] * scale;
          if (diag) {
            const int key = kv * 64 + n * 16 + lo;
            const int qr = q0 + w * 16 + hi * 4 + r;
            if (key > qr) v = -INFINITY;
          }
          sv[n][r] = v;
        }

      float mx[4];
#pragma unroll
      for (int r = 0; r < 4; ++r) {
        mx[r] = fmaxf(fmaxf(sv[0][r], sv[1][r]), fmaxf(sv[2][r], sv[3][r]));
#pragma unroll
        for (int off = 1; off < 16; off <<= 1)
          mx[r] = fmaxf(mx[r], __shfl_xor(mx[r], off));
      }
      float corr[4], p[4][4], rs[4];
#pragma unroll
      for (int r = 0; r < 4; ++r) {
        const float mnew = fmaxf(m_s[r], mx[r]);
        corr[r] = __expf(m_s[r] - mnew);
        m_s[r] = mnew;
        rs[r] = 0.f;
      }
#pragma unroll
      for (int n = 0; n < 4; ++n)
#pragma unroll
        for (int r = 0; r < 4; ++r) {
          p[n][r] = __expf(sv[n][r] - m_s[r]);
          rs[r] += p[n][r];
        }
#pragma unroll
      for (int r = 0; r < 4; ++r) {
#pragma unroll
        for (int off = 1; off < 16; off <<= 1) rs[r] += __shfl_xor(rs[r], off);
        l_s[r] = l_s[r] * corr[r] + rs[r];
      }
#pragma unroll
      for (int n = 0; n < 8; ++n)
#pragma unroll
        for (int r = 0; r < 4; ++r) accO[n][r] *= corr[r];

#pragma unroll
      for (int n = 0; n < 4; ++n)
#pragma unroll
        for (int r = 0; r < 4; ++r) {
          const int row = hi * 4 + r;
          __bf16 h = (__bf16)p[n][r];
          *(unsigned short*)((char*)&Psm[w][0] + row * 128 +
                             (((n * 16 + lo) * 2) ^ ((row & 7) << 4))) =
              __builtin_bit_cast(unsigned short, h);
        }

      if (more) WRITE_VT(cur ^ 1);

      const char* vsm = (const char*)&Vtsm[cur][0];
#pragma unroll
      for (int k2 = 0; k2 < 2; ++k2) {
        const int cb = k2 * 64 + hi * 16;
        const v8bf aP = *(const v8bf*)((const char*)&Psm[w][0] + lo * 128 + (cb ^ ((lo & 7) << 4)));
#pragma unroll
        for (int n = 0; n < 8; ++n) {
          const int r = n * 16 + lo;
          const v8bf bv = *(const v8bf*)(vsm + r * 128 + (cb ^ ((r & 7) << 4)));
          accO[n] = __builtin_amdgcn_mfma_f32_16x16x32_bf16(aP, bv, accO[n], 0, 0, 0);
        }
      }
      if (more) __syncthreads();
    }
  }

  // store partials: unnormalized O (bf16), m, l
#pragma unroll
  for (int r = 0; r < 4; ++r) {
    const int qr = q0 + w * 16 + hi * 4 + r;
    __bf16* op = Opart + ((size_t)s * NROWS + b * SEQ + qr) * HD + lo;
#pragma unroll
    for (int n = 0; n < 8; ++n) op[n * 16] = (__bf16)accO[n][r];
    if (lo == 0) {
      float* mlp = Ml + ((size_t)s * NROWS + b * SEQ + qr) * 2;
      mlp[0] = m_s[r];
      mlp[1] = l_s[r];
    }
  }
}

// ---------------- combine the four KV-chunk partials ----------------
__global__ __launch_bounds__(256) void combine_kernel(
    const __bf16* __restrict__ Opart, const float* __restrict__ Ml,
    float* __restrict__ out)
{
  const int idx = blockIdx.x * 256 + threadIdx.x;  // 0..65535
  const int row = idx >> 2, ch = idx & 3;          // 32-col chunk
  float m[4], l[4];
#pragma unroll
  for (int s = 0; s < 4; ++s) {
    const float* mlp = Ml + ((size_t)s * NROWS + row) * 2;
    m[s] = mlp[0];
    l[s] = mlp[1];
  }
  const float M = fmaxf(fmaxf(m[0], m[1]), fmaxf(m[2], m[3]));
  float e[4], denom = 0.f;
#pragma unroll
  for (int s = 0; s < 4; ++s) { e[s] = __expf(m[s] - M); denom += l[s] * e[s]; }
  const float inv = 1.f / denom;

  float* po = out + (size_t)row * HD + ch * 32;
#pragma unroll
  for (int j = 0; j < 4; ++j) {     // 4 groups of 8 cols
    float sum[8];
#pragma unroll
    for (int q2 = 0; q2 < 8; ++q2) sum[q2] = 0.f;
#pragma unroll
    for (int s = 0; s < 4; ++s) {
      U8 o;
      o.v = *(const v8bf*)(Opart + ((size_t)s * NROWS + row) * HD + ch * 32 + j * 8);
#pragma unroll
      for (int q2 = 0; q2 < 8; ++q2) sum[q2] += (float)o.b[q2] * e[s];
    }
#pragma unroll
    for (int q2 = 0; q2 < 8; ++q2) po[j * 8 + q2] = sum[q2] * inv;
  }
}

extern "C" void kernel_launch(void* const* d_in, const int* in_sizes, int n_in,
                              void* d_out, int out_size, void* d_ws, size_t ws_size,
                              hipStream_t stream) {
  const float* x  = (const float*)d_in[0];
  const float* Wq = (const float*)d_in[1];
  const float* bq = (const float*)d_in[2];
  const float* Wk = (const float*)d_in[3];
  const float* bk = (const float*)d_in[4];
  const float* Wv = (const float*)d_in[5];
  const float* bv = (const float*)d_in[6];
  float* out = (float*)d_out;

  // workspace (~30 MiB)
  __bf16* Qb = (__bf16*)d_ws;                        // 16384x128 bf16 each
  __bf16* Kb = Qb + (size_t)NROWS * HD;
  __bf16* Vb = Kb + (size_t)NROWS * HD;
  __bf16* Wb = Vb + (size_t)NROWS * HD;              // 3 x 128 x 2048 bf16
  __bf16* Opart = Wb + (size_t)3 * HD * NEMB;        // 4 x 16384 x 128 bf16
  float*  Ml = (float*)(Opart + (size_t)4 * NROWS * HD);  // 4 x 16384 x 2 fp32

  wconv_kernel<<<dim3(3 * 64), dim3(256), 0, stream>>>(Wq, Wk, Wv, Wb);
  qkv_fused_kernel<<<dim3(256), dim3(512), 0, stream>>>(
      x, Wb, bq, bk, bv, Qb, Kb, Vb);
  attn_kernel<<<dim3(BATCH * 32 * 4), dim3(256), 0, stream>>>(Qb, Kb, Vb, Opart, Ml);
  combine_kernel<<<dim3(NROWS * 4 / 256), dim3(256), 0, stream>>>(Opart, Ml, out);
}